// Round 17
// baseline (412.696 us; speedup 1.0000x reference)
//
#include <hip/hip_runtime.h>
#include <hip/hip_fp16.h>

typedef _Float16 half8 __attribute__((ext_vector_type(8)));
typedef float f32x4 __attribute__((ext_vector_type(4)));
typedef float f32x16 __attribute__((ext_vector_type(16)));

#define HID 128
#define NDIM 16
#define NCONV 8
#define ECAP 64   // slot capacity per node; Poisson(16) max deg ~40 << 64

static __device__ __forceinline__ half8 load_h8(const _Float16* p) {
    return *(const half8*)p;
}

static __device__ __forceinline__ float treemax16(const f32x16& d) {
    float m0 = fmaxf(fmaxf(d[0], d[1]), fmaxf(d[2], d[3]));
    float m1 = fmaxf(fmaxf(d[4], d[5]), fmaxf(d[6], d[7]));
    float m2 = fmaxf(fmaxf(d[8], d[9]), fmaxf(d[10], d[11]));
    float m3 = fmaxf(fmaxf(d[12], d[13]), fmaxf(d[14], d[15]));
    return fmaxf(fmaxf(m0, m1), fmaxf(m2, m3));
}

// ---------------- weight prep + slot-table edge fill ----------------
__global__ void prep_weights(const float* __restrict__ W1, const float* __restrict__ W2,
                             const float* __restrict__ dW, const float* __restrict__ b1,
                             const float* __restrict__ eW, const int* __restrict__ ei,
                             _Float16* __restrict__ WABT, _Float16* __restrict__ W2T,
                             _Float16* __restrict__ dWT, float* __restrict__ biasAB,
                             _Float16* __restrict__ eW16,
                             int* __restrict__ cnt, int* __restrict__ eltab, int E) {
    int idx = blockIdx.x * blockDim.x + threadIdx.x;
    int total = NCONV * HID * HID;
    if (idx < total) {
        int l = idx / (HID * HID);
        int r = idx % (HID * HID);
        int k = r / HID;        // slow: input row
        int j = r % HID;        // fast: input col -> coalesced loads
        const float* w1 = W1 + (size_t)l * 2 * HID * HID;
        float top = w1[k * HID + j];
        float bot = w1[(HID + k) * HID + j];
        _Float16* wab = WABT + (size_t)l * 2 * HID * HID;
        wab[j * HID + k] = (_Float16)(top - bot);
        wab[(HID + j) * HID + k] = (_Float16)bot;
        const float* w2 = W2 + (size_t)l * HID * HID;
        W2T[(size_t)l * HID * HID + j * HID + k] = (_Float16)w2[k * HID + j];
    } else if (idx < total + 16 * HID) {
        int r = idx - total;
        int j = r / HID;        // 0..15
        int k = r % HID;
        dWT[j * HID + k] = (_Float16)dW[k * NDIM + j];
    } else if (idx < total + 16 * HID + NCONV * 256) {
        int r = idx - total - 16 * HID;
        int l = r >> 8;
        int c = r & 255;
        biasAB[l * 256 + c] = (c < HID) ? b1[l * HID + c] : 0.f;
    } else if (idx < total + 16 * HID + NCONV * 256 + HID * HID) {
        int r = idx - total - 16 * HID - NCONV * 256;
        eW16[r] = (_Float16)eW[r];           // straight cast, coalesced
    }
    // edge fill (all threads, grid-stride); slot order race-dependent but the ec
    // max-reduction is order-invariant -> deterministic OUTPUT.
    int gsz = gridDim.x * blockDim.x;
    for (int e = idx; e < E; e += gsz) {
        int dv = ei[E + e];
        int pos = atomicAdd(&cnt[dv], 1);
        if (pos < ECAP) eltab[(size_t)dv * ECAP + pos] = ei[e];
    }
}

// ---------------- node_emb + layer-0 ab + enc-fold (one dispatch) ----------------
__global__ __launch_bounds__(512) void node_emb_ab(const float* __restrict__ x,
                                                   const float* __restrict__ t,
                                                   const float* __restrict__ tpW,
                                                   const float* __restrict__ tpb,
                                                   const float* __restrict__ neW,
                                                   const float* __restrict__ neb,
                                                   const _Float16* __restrict__ WABT0,
                                                   const float* __restrict__ biasAB0,
                                                   _Float16* __restrict__ Atab,
                                                   _Float16* __restrict__ Btab,
                                                   const _Float16* __restrict__ eW16,
                                                   const _Float16* __restrict__ WABT4old,
                                                   const float* __restrict__ b1_4,
                                                   const float* __restrict__ eb,
                                                   _Float16* __restrict__ WENC,
                                                   float* __restrict__ biasENC, int n) {
    int bid = blockIdx.x;
    int tid = threadIdx.x;
    int ngroups = (n + 15) >> 4;
    int lane = tid & 63;
    int wv = tid >> 6;
    int c = lane & 15;
    int kq = lane >> 4;

    if (bid >= ngroups) {
        int xb = bid - ngroups;
        if (xb < 16) {           // enc-fold GEMM: 8 output tiles per block
            int gw = xb * 8 + wv;          // 0..127
            int jt = gw >> 3;              // 0..15 (256 output cols)
            int kt = gw & 7;               // 0..7  (128 k)
            half8 a[4], b[4];
            #pragma unroll
            for (int kb = 0; kb < 4; kb++) {
                a[kb] = load_h8(eW16 + (size_t)(kt * 16 + c) * HID + kb * 32 + kq * 8);
                b[kb] = load_h8(WABT4old + (size_t)(jt * 16 + c) * HID + kb * 32 + kq * 8);
            }
            f32x4 acc = {0.f, 0.f, 0.f, 0.f};
            #pragma unroll
            for (int kb = 0; kb < 4; kb++)
                acc = __builtin_amdgcn_mfma_f32_16x16x32_f16(a[kb], b[kb], acc, 0, 0, 0);
            #pragma unroll
            for (int r = 0; r < 4; r++)
                WENC[(size_t)(jt * 16 + c) * HID + kt * 16 + kq * 4 + r] = (_Float16)acc[r];
        } else if (tid < 256) {  // enc-fold biases
            float acc = (tid < HID) ? b1_4[tid] : 0.f;
            const _Float16* row = WABT4old + (size_t)tid * HID;
            for (int q = 0; q < HID; q++) acc += eb[q] * (float)row[q];
            biasENC[tid] = acc;
        }
        return;
    }

    __shared__ float sc[64];
    __shared__ float temb[NDIM];
    __shared__ _Float16 hlds[16][136];
    float tv = t[0];
    if (tid < 32) {
        float f = expf(-4.0f + 8.0f * (float)tid / 31.0f);
        sc[tid] = sinf(tv * f);
        sc[32 + tid] = cosf(tv * f);
    }
    __syncthreads();
    if (tid < 16) {
        float acc = tpb[tid];
        for (int k = 0; k < 64; k++) acc += sc[k] * tpW[k * NDIM + tid];
        temb[tid] = acc;
    }
    __syncthreads();

    int gbase = bid * 16;
    for (int idx = tid; idx < 16 * HID; idx += 512) {
        int r = idx >> 7;
        int j = idx & 127;
        int v = gbase + r;
        float acc = 0.f;
        if (v < n) {
            const float* xr = x + (size_t)v * NDIM;
            acc = neb[j];
            #pragma unroll
            for (int d = 0; d < NDIM; d++) acc += (xr[d] + temb[d]) * neW[d * HID + j];
        }
        hlds[r][j] = (_Float16)acc;
    }
    __syncthreads();

    // ab phase (identical to fused_conv's)
    half8 a[4];
    #pragma unroll
    for (int kb = 0; kb < 4; kb++)
        a[kb] = load_h8(&hlds[c][kb * 32 + kq * 8]);
    #pragma unroll
    for (int p = 0; p < 2; p++) {
        int jt = wv + p * 8;
        int wrow = jt * 16 + c;
        f32x4 acc = {0.f, 0.f, 0.f, 0.f};
        #pragma unroll
        for (int kb = 0; kb < 4; kb++) {
            half8 b = load_h8(WABT0 + (size_t)wrow * HID + kb * 32 + kq * 8);
            acc = __builtin_amdgcn_mfma_f32_16x16x32_f16(a[kb], b, acc, 0, 0, 0);
        }
        float bv = biasAB0[wrow];
        _Float16* dst = (wrow < HID) ? Atab : Btab;
        int dcol = wrow & (HID - 1);
        #pragma unroll
        for (int r = 0; r < 4; r++) {
            int row = gbase + kq * 4 + r;
            if (row < n) dst[(size_t)row * HID + dcol] = (_Float16)(acc[r] + bv);
        }
    }
}

// ======================= fused ec_l + ab_{l+1} (or + fc_dec if last) =======================
// DUAL-NODE INTERLEAVED ec (r16 diagnosis: LDS W2 reads ~4us/layer = largest pipe; 2
// serial nodes/wave left gathers unoverlapped). Each wave gathers BOTH its nodes'
// tile-0 rows up front (2x gather MLP), then per CB block reads each W2 fragment ONCE
// feeding two MFMA streams (dA,dB) -> LDS traffic per node HALVED. Live set ~116 VGPR;
// __launch_bounds__(512,4) caps at 128 (est. headroom ~12 — r2's spill was 150-vs-128).
// 2 blocks/CU resident (512 of 625 concurrent; mild tail traded for pipe savings).
// deg>31 nodes (P~2e-4): wave-uniform fallback to single-node extra tiles.
__global__ __launch_bounds__(512, 4) void fused_conv(const _Float16* __restrict__ Acur,
                                                     const _Float16* __restrict__ Bcur,
                                                     const _Float16* __restrict__ W2T_l,
                                                     const float* __restrict__ b2_l,
                                                     const int* __restrict__ cnt,
                                                     const int* __restrict__ eltab,
                                                     const _Float16* __restrict__ WABT_n,
                                                     const float* __restrict__ biasAB_n,
                                                     _Float16* __restrict__ Anxt,
                                                     _Float16* __restrict__ Bnxt,
                                                     const _Float16* __restrict__ dWT,
                                                     const float* __restrict__ db,
                                                     float* __restrict__ out,
                                                     int last, int n) {
    __shared__ _Float16 w2s[2048 * 8];     // 32 KB, fragment-major (0-conflict, r3)
    __shared__ float b2s[HID];
    __shared__ _Float16 hlds[16][136];

    int tid = threadIdx.x;
    #pragma unroll
    for (int i = 0; i < 4; i++) {
        int fid = i * 512 + tid;           // 0..2047
        int ln = fid & 63;
        int grp = fid >> 6;                // kb*4+cb
        int kb = grp >> 2;
        int cb = grp & 3;
        *(half8*)(w2s + (size_t)fid * 8) =
            load_h8(W2T_l + (size_t)(cb * 32 + (ln & 31)) * HID + kb * 16 + (ln >> 5) * 8);
    }
    if (tid < HID) b2s[tid] = b2_l[tid];
    __syncthreads();

    int lane = tid & 63;
    int wv = tid >> 6;          // 0..7
    int er = lane & 31;
    int hi = lane >> 5;
    int c = lane & 15;
    int kq = lane >> 4;

    int g = blockIdx.x;
    int gbase = g * 16;

    int vA = gbase + wv;
    int vB = gbase + wv + 8;
    int dgA = 0, dgB = 0;
    if (vA < n) { dgA = cnt[vA]; dgA = (dgA > ECAP) ? ECAP : dgA; }
    if (vB < n) { dgB = cnt[vB]; dgB = (dgB > ECAP) ? ECAP : dgB; }
    int srcA = (er < dgA) ? eltab[(size_t)vA * ECAP + er] : ((vA < n) ? vA : 0);
    int srcB = (er < dgB) ? eltab[(size_t)vB * ECAP + er] : ((vB < n) ? vB : 0);
    int vAc = (vA < n) ? vA : 0;   // clamped for safe (discarded) loads
    int vBc = (vB < n) ? vB : 0;

    // ---- gather+relu of one 32-edge tile into s ----
    auto gather_relu = [&](const _Float16* ap, const _Float16* bp, half8* s) {
        #pragma unroll
        for (int kb = 0; kb < 8; kb++) {
            half8 t2 = load_h8(ap + kb * 16) + load_h8(bp + kb * 16);
            #pragma unroll
            for (int e2 = 0; e2 < 8; e2++) t2[e2] = (t2[e2] > (_Float16)0) ? t2[e2] : (_Float16)0;
            s[kb] = t2;
        }
    };

    float mA0 = -3.0e38f, mA1 = -3.0e38f, mA2 = -3.0e38f, mA3 = -3.0e38f;
    float mB0 = -3.0e38f, mB1 = -3.0e38f, mB2 = -3.0e38f, mB3 = -3.0e38f;

    // ---- combined tile 0 of both nodes: shared W2 reads, dual MFMA streams ----
    {
        half8 sA[8], sB[8];
        gather_relu(Acur + (size_t)vAc * HID + hi * 8, Bcur + (size_t)srcA * HID + hi * 8, sA);
        gather_relu(Acur + (size_t)vBc * HID + hi * 8, Bcur + (size_t)srcB * HID + hi * 8, sB);

#define CB2(CB, MA, MB)                                                                 \
        {                                                                               \
            f32x16 dA, dB;                                                              \
            _Pragma("unroll")                                                           \
            for (int e2 = 0; e2 < 16; e2++) { dA[e2] = 0.f; dB[e2] = 0.f; }             \
            _Pragma("unroll")                                                           \
            for (int kb = 0; kb < 8; kb++) {                                            \
                half8 w = *(const half8*)(w2s + ((size_t)((kb * 4 + CB) * 64 + lane)) * 8); \
                dA = __builtin_amdgcn_mfma_f32_32x32x16_f16(sA[kb], w, dA, 0, 0, 0);    \
                dB = __builtin_amdgcn_mfma_f32_32x32x16_f16(sB[kb], w, dB, 0, 0, 0);    \
            }                                                                           \
            MA = fmaxf(MA, treemax16(dA));                                              \
            MB = fmaxf(MB, treemax16(dB));                                              \
        }
        CB2(0, mA0, mB0)
        __builtin_amdgcn_sched_barrier(0);
        CB2(1, mA1, mB1)
        __builtin_amdgcn_sched_barrier(0);
        CB2(2, mA2, mB2)
        __builtin_amdgcn_sched_barrier(0);
        CB2(3, mA3, mB3)
#undef CB2
    }

    // ---- rare extra tiles (deg > 31), single-node path; wave-uniform branch ----
    auto ec_extra = [&](int v, int dg, float& m0, float& m1, float& m2, float& m3) {
        int ntile = (dg + 32) >> 5;
        for (int tI = 1; tI < ntile; tI++) {
            int en = tI * 32 + er;
            int src = (en < dg) ? eltab[(size_t)v * ECAP + en] : v;
            half8 s[8];
            gather_relu(Acur + (size_t)v * HID + hi * 8, Bcur + (size_t)src * HID + hi * 8, s);
#define CB1(CB, MREF)                                                                   \
            {                                                                           \
                f32x16 d;                                                               \
                _Pragma("unroll")                                                       \
                for (int e2 = 0; e2 < 16; e2++) d[e2] = 0.f;                            \
                _Pragma("unroll")                                                       \
                for (int kb = 0; kb < 8; kb++) {                                        \
                    half8 w = *(const half8*)(w2s + ((size_t)((kb * 4 + CB) * 64 + lane)) * 8); \
                    d = __builtin_amdgcn_mfma_f32_32x32x16_f16(s[kb], w, d, 0, 0, 0);   \
                }                                                                       \
                MREF = fmaxf(MREF, treemax16(d));                                       \
            }
            CB1(0, m0)
            __builtin_amdgcn_sched_barrier(0);
            CB1(1, m1)
            __builtin_amdgcn_sched_barrier(0);
            CB1(2, m2)
            __builtin_amdgcn_sched_barrier(0);
            CB1(3, m3)
#undef CB1
        }
    };
    if (dgA > 31) ec_extra(vA, dgA, mA0, mA1, mA2, mA3);
    if (dgB > 31) ec_extra(vB, dgB, mB0, mB1, mB2, mB3);

    // ---- merge k-halves, write h rows to LDS ----
    {
        float a0 = fmaxf(mA0, __shfl_xor(mA0, 32)) + b2s[er];
        float a1 = fmaxf(mA1, __shfl_xor(mA1, 32)) + b2s[32 + er];
        float a2 = fmaxf(mA2, __shfl_xor(mA2, 32)) + b2s[64 + er];
        float a3 = fmaxf(mA3, __shfl_xor(mA3, 32)) + b2s[96 + er];
        float b0 = fmaxf(mB0, __shfl_xor(mB0, 32)) + b2s[er];
        float b1 = fmaxf(mB1, __shfl_xor(mB1, 32)) + b2s[32 + er];
        float b2 = fmaxf(mB2, __shfl_xor(mB2, 32)) + b2s[64 + er];
        float b3 = fmaxf(mB3, __shfl_xor(mB3, 32)) + b2s[96 + er];
        if (lane < 32) {
            hlds[wv][er]          = (_Float16)a0;
            hlds[wv][32 + er]     = (_Float16)a1;
            hlds[wv][64 + er]     = (_Float16)a2;
            hlds[wv][96 + er]     = (_Float16)a3;
            hlds[wv + 8][er]      = (_Float16)b0;
            hlds[wv + 8][32 + er] = (_Float16)b1;
            hlds[wv + 8][64 + er] = (_Float16)b2;
            hlds[wv + 8][96 + er] = (_Float16)b3;
        }
    }
    __syncthreads();

    if (!last) {
        // ---- ab phase: this wave does j-tiles wv and wv+8 (A-frags read once) ----
        half8 a[4];
        #pragma unroll
        for (int kb = 0; kb < 4; kb++)
            a[kb] = load_h8(&hlds[c][kb * 32 + kq * 8]);
        #pragma unroll
        for (int p = 0; p < 2; p++) {
            int jt = wv + p * 8;           // 0..15
            int wrow = jt * 16 + c;        // output col 0..255
            f32x4 acc = {0.f, 0.f, 0.f, 0.f};
            #pragma unroll
            for (int kb = 0; kb < 4; kb++) {
                half8 b = load_h8(WABT_n + (size_t)wrow * HID + kb * 32 + kq * 8);
                acc = __builtin_amdgcn_mfma_f32_16x16x32_f16(a[kb], b, acc, 0, 0, 0);
            }
            float bv = biasAB_n[wrow];
            _Float16* dst = (wrow < HID) ? Anxt : Bnxt;
            int dcol = wrow & (HID - 1);
            #pragma unroll
            for (int r = 0; r < 4; r++) {
                int row = gbase + kq * 4 + r;
                if (row < n) dst[(size_t)row * HID + dcol] = (_Float16)(acc[r] + bv);
            }
        }
    } else if (wv == 0) {
        // ---- fc_dec: out[gbase..+16][16] = h @ dWT^T + db ----
        half8 a[4];
        #pragma unroll
        for (int kb = 0; kb < 4; kb++)
            a[kb] = load_h8(&hlds[c][kb * 32 + kq * 8]);
        f32x4 acc = {0.f, 0.f, 0.f, 0.f};
        #pragma unroll
        for (int kb = 0; kb < 4; kb++) {
            half8 b = load_h8(dWT + (size_t)c * HID + kb * 32 + kq * 8);
            acc = __builtin_amdgcn_mfma_f32_16x16x32_f16(a[kb], b, acc, 0, 0, 0);
        }
        float bv = db[c];
        #pragma unroll
        for (int r = 0; r < 4; r++) {
            int row = gbase + kq * 4 + r;
            if (row < n) out[(size_t)row * NDIM + c] = acc[r] + bv;
        }
    }
}

// ---------------- host ----------------
extern "C" void kernel_launch(void* const* d_in, const int* in_sizes, int n_in,
                              void* d_out, int out_size, void* d_ws, size_t ws_size,
                              hipStream_t stream) {
    const float* x   = (const float*)d_in[0];
    const int*   ei  = (const int*)d_in[1];
    const float* t   = (const float*)d_in[2];
    const float* neW = (const float*)d_in[3];
    const float* neb = (const float*)d_in[4];
    const float* cW1 = (const float*)d_in[5];
    const float* cb1 = (const float*)d_in[6];
    const float* cW2 = (const float*)d_in[7];
    const float* cb2 = (const float*)d_in[8];
    const float* eW  = (const float*)d_in[9];
    const float* eb  = (const float*)d_in[10];
    const float* dW  = (const float*)d_in[11];
    const float* db  = (const float*)d_in[12];
    const float* tpW = (const float*)d_in[13];
    const float* tpb = (const float*)d_in[14];

    int N = in_sizes[0] / NDIM;
    int E = in_sizes[1] / 2;

    char* w = (char*)d_ws;
    auto alloc = [&](size_t bytes) {
        void* p = (void*)w;
        w += (bytes + 255) & ~(size_t)255;
        return p;
    };
    _Float16*  Atab0  = (_Float16*)alloc((size_t)N * HID * 2);
    _Float16*  Btab0  = (_Float16*)alloc((size_t)N * HID * 2);
    _Float16*  Atab1  = (_Float16*)alloc((size_t)N * HID * 2);
    _Float16*  Btab1  = (_Float16*)alloc((size_t)N * HID * 2);
    _Float16*  WABT   = (_Float16*)alloc((size_t)NCONV * 2 * HID * HID * 2);
    _Float16*  W2T    = (_Float16*)alloc((size_t)NCONV * HID * HID * 2);
    _Float16*  dWT    = (_Float16*)alloc((size_t)16 * HID * 2);
    _Float16*  eW16   = (_Float16*)alloc((size_t)HID * HID * 2);
    _Float16*  WENC   = (_Float16*)alloc((size_t)2 * HID * HID * 2);
    float*     biasAB = (float*)alloc((size_t)NCONV * 256 * 4);
    float*     biasENC= (float*)alloc((size_t)256 * 4);
    int*       cnt    = (int*)alloc((size_t)N * 4);
    int*       eltab  = (int*)alloc((size_t)N * ECAP * 4);

    // 1: zero slot cursors
    hipMemsetAsync(cnt, 0, (size_t)N * 4, stream);
    // 2: weights + slot-table edge fill
    int prep_total = NCONV * HID * HID + 16 * HID + NCONV * 256 + HID * HID;
    prep_weights<<<(prep_total + 255) / 256, 256, 0, stream>>>(cW1, cW2, dW, cb1, eW, ei,
                                                               WABT, W2T, dWT, biasAB,
                                                               eW16, cnt, eltab, E);
    // 3: node emb + layer-0 ab + enc fold
    int nmt = (N + 15) / 16;
    node_emb_ab<<<nmt + 17, 512, 0, stream>>>(x, t, tpW, tpb, neW, neb,
                                              WABT, biasAB, Atab0, Btab0,
                                              eW16, WABT + (size_t)4 * 2 * HID * HID,
                                              cb1 + (size_t)4 * HID, eb, WENC, biasENC, N);

    // 4..11: fused conv layers
    for (int l = 0; l < NCONV; l++) {
        const _Float16* Acur = (l & 1) ? Atab1 : Atab0;
        const _Float16* Bcur = (l & 1) ? Btab1 : Btab0;
        _Float16* Anxt = (l & 1) ? Atab0 : Atab1;
        _Float16* Bnxt = (l & 1) ? Btab0 : Btab1;
        int ln = (l + 1 < NCONV) ? (l + 1) : 0;   // dummy (unused) when last
        const _Float16* wabn = (l == 3) ? WENC : WABT + (size_t)ln * 2 * HID * HID;
        const float*    babn = (l == 3) ? biasENC : biasAB + (size_t)ln * 256;
        fused_conv<<<nmt, 512, 0, stream>>>(Acur, Bcur,
                                            W2T + (size_t)l * HID * HID,
                                            cb2 + (size_t)l * HID,
                                            cnt, eltab,
                                            wabn, babn,
                                            Anxt, Bnxt,
                                            dWT, db, (float*)d_out,
                                            (l == NCONV - 1) ? 1 : 0, N);
    }
}

// Round 18
// 253.947 us; speedup vs baseline: 1.6251x; 1.6251x over previous
//
#include <hip/hip_runtime.h>
#include <hip/hip_fp16.h>

typedef _Float16 half8 __attribute__((ext_vector_type(8)));
typedef float f32x4 __attribute__((ext_vector_type(4)));
typedef float f32x16 __attribute__((ext_vector_type(16)));

#define HID 128
#define NDIM 16
#define NCONV 8
#define ECAP 64   // slot capacity per node; Poisson(16) max deg ~40 << 64

static __device__ __forceinline__ half8 load_h8(const _Float16* p) {
    return *(const half8*)p;
}

// ---------------- weight prep + slot-table edge fill ----------------
// WABT[l] rows j<128: W1A_T[j][k]=W1[k][j]-W1[128+k][j]; rows 128+j: W1B_T[j][k]=W1[128+k][j]
// W2T[l][j][k] = W2[k][j].  Tails: dWT, biasAB, eW16 (f16 cast of eW).
// Then grid-stride edge fill: eltab[dst][slot]=src via atomic cursor (cnt memset to 0
// beforehand). Slot order is race-dependent but ec's max-reduction is order-invariant,
// so the OUTPUT is deterministic. Replaces count->scan->fill (the serial scan_csr).
__global__ void prep_weights(const float* __restrict__ W1, const float* __restrict__ W2,
                             const float* __restrict__ dW, const float* __restrict__ b1,
                             const float* __restrict__ eW, const int* __restrict__ ei,
                             _Float16* __restrict__ WABT, _Float16* __restrict__ W2T,
                             _Float16* __restrict__ dWT, float* __restrict__ biasAB,
                             _Float16* __restrict__ eW16,
                             int* __restrict__ cnt, int* __restrict__ eltab, int E) {
    int idx = blockIdx.x * blockDim.x + threadIdx.x;
    int total = NCONV * HID * HID;
    if (idx < total) {
        int l = idx / (HID * HID);
        int r = idx % (HID * HID);
        int k = r / HID;        // slow: input row
        int j = r % HID;        // fast: input col -> coalesced loads
        const float* w1 = W1 + (size_t)l * 2 * HID * HID;
        float top = w1[k * HID + j];
        float bot = w1[(HID + k) * HID + j];
        _Float16* wab = WABT + (size_t)l * 2 * HID * HID;
        wab[j * HID + k] = (_Float16)(top - bot);
        wab[(HID + j) * HID + k] = (_Float16)bot;
        const float* w2 = W2 + (size_t)l * HID * HID;
        W2T[(size_t)l * HID * HID + j * HID + k] = (_Float16)w2[k * HID + j];
    } else if (idx < total + 16 * HID) {
        int r = idx - total;
        int j = r / HID;        // 0..15
        int k = r % HID;
        dWT[j * HID + k] = (_Float16)dW[k * NDIM + j];
    } else if (idx < total + 16 * HID + NCONV * 256) {
        int r = idx - total - 16 * HID;
        int l = r >> 8;
        int c = r & 255;
        biasAB[l * 256 + c] = (c < HID) ? b1[l * HID + c] : 0.f;
    } else if (idx < total + 16 * HID + NCONV * 256 + HID * HID) {
        int r = idx - total - 16 * HID - NCONV * 256;
        eW16[r] = (_Float16)eW[r];           // straight cast, coalesced
    }
    // edge fill (all threads, grid-stride)
    int gsz = gridDim.x * blockDim.x;
    for (int e = idx; e < E; e += gsz) {
        int dv = ei[E + e];
        int pos = atomicAdd(&cnt[dv], 1);
        if (pos < ECAP) eltab[(size_t)dv * ECAP + pos] = ei[e];
    }
}

// ---------------- node_emb + layer-0 ab + enc-fold (one dispatch) ----------------
// Blocks 0..ngroups-1: compute the group's 16 h-rows (x+temb)@neW+neb into LDS, then
// the fused_conv ab phase (wave wv -> j-tiles wv, wv+8) producing Atab0/Btab0.
// Blocks ngroups..ngroups+15: enc-fold GEMM (WENC = (E@W1_4) transposed-f16).
// Block ngroups+16: enc-fold biases (biasENC = eb@W1_4 + b1_4 | eb@W1B_4).
__global__ __launch_bounds__(512) void node_emb_ab(const float* __restrict__ x,
                                                   const float* __restrict__ t,
                                                   const float* __restrict__ tpW,
                                                   const float* __restrict__ tpb,
                                                   const float* __restrict__ neW,
                                                   const float* __restrict__ neb,
                                                   const _Float16* __restrict__ WABT0,
                                                   const float* __restrict__ biasAB0,
                                                   _Float16* __restrict__ Atab,
                                                   _Float16* __restrict__ Btab,
                                                   const _Float16* __restrict__ eW16,
                                                   const _Float16* __restrict__ WABT4old,
                                                   const float* __restrict__ b1_4,
                                                   const float* __restrict__ eb,
                                                   _Float16* __restrict__ WENC,
                                                   float* __restrict__ biasENC, int n) {
    int bid = blockIdx.x;
    int tid = threadIdx.x;
    int ngroups = (n + 15) >> 4;
    int lane = tid & 63;
    int wv = tid >> 6;
    int c = lane & 15;
    int kq = lane >> 4;

    if (bid >= ngroups) {
        int xb = bid - ngroups;
        if (xb < 16) {           // enc-fold GEMM: 8 output tiles per block
            int gw = xb * 8 + wv;          // 0..127
            int jt = gw >> 3;              // 0..15 (256 output cols)
            int kt = gw & 7;               // 0..7  (128 k)
            half8 a[4], b[4];
            #pragma unroll
            for (int kb = 0; kb < 4; kb++) {
                a[kb] = load_h8(eW16 + (size_t)(kt * 16 + c) * HID + kb * 32 + kq * 8);
                b[kb] = load_h8(WABT4old + (size_t)(jt * 16 + c) * HID + kb * 32 + kq * 8);
            }
            f32x4 acc = {0.f, 0.f, 0.f, 0.f};
            #pragma unroll
            for (int kb = 0; kb < 4; kb++)
                acc = __builtin_amdgcn_mfma_f32_16x16x32_f16(a[kb], b[kb], acc, 0, 0, 0);
            #pragma unroll
            for (int r = 0; r < 4; r++)
                WENC[(size_t)(jt * 16 + c) * HID + kt * 16 + kq * 4 + r] = (_Float16)acc[r];
        } else if (tid < 256) {  // enc-fold biases
            float acc = (tid < HID) ? b1_4[tid] : 0.f;
            const _Float16* row = WABT4old + (size_t)tid * HID;
            for (int q = 0; q < HID; q++) acc += eb[q] * (float)row[q];
            biasENC[tid] = acc;
        }
        return;
    }

    __shared__ float sc[64];
    __shared__ float temb[NDIM];
    __shared__ _Float16 hlds[16][136];
    float tv = t[0];
    if (tid < 32) {
        float f = expf(-4.0f + 8.0f * (float)tid / 31.0f);
        sc[tid] = sinf(tv * f);
        sc[32 + tid] = cosf(tv * f);
    }
    __syncthreads();
    if (tid < 16) {
        float acc = tpb[tid];
        for (int k = 0; k < 64; k++) acc += sc[k] * tpW[k * NDIM + tid];
        temb[tid] = acc;
    }
    __syncthreads();

    int gbase = bid * 16;
    for (int idx = tid; idx < 16 * HID; idx += 512) {
        int r = idx >> 7;
        int j = idx & 127;
        int v = gbase + r;
        float acc = 0.f;
        if (v < n) {
            const float* xr = x + (size_t)v * NDIM;
            acc = neb[j];
            #pragma unroll
            for (int d = 0; d < NDIM; d++) acc += (xr[d] + temb[d]) * neW[d * HID + j];
        }
        hlds[r][j] = (_Float16)acc;
    }
    __syncthreads();

    // ab phase (identical to fused_conv's)
    half8 a[4];
    #pragma unroll
    for (int kb = 0; kb < 4; kb++)
        a[kb] = load_h8(&hlds[c][kb * 32 + kq * 8]);
    #pragma unroll
    for (int p = 0; p < 2; p++) {
        int jt = wv + p * 8;
        int wrow = jt * 16 + c;
        f32x4 acc = {0.f, 0.f, 0.f, 0.f};
        #pragma unroll
        for (int kb = 0; kb < 4; kb++) {
            half8 b = load_h8(WABT0 + (size_t)wrow * HID + kb * 32 + kq * 8);
            acc = __builtin_amdgcn_mfma_f32_16x16x32_f16(a[kb], b, acc, 0, 0, 0);
        }
        float bv = biasAB0[wrow];
        _Float16* dst = (wrow < HID) ? Atab : Btab;
        int dcol = wrow & (HID - 1);
        #pragma unroll
        for (int r = 0; r < 4; r++) {
            int row = gbase + kq * 4 + r;
            if (row < n) dst[(size_t)row * HID + dcol] = (_Float16)(acc[r] + bv);
        }
    }
}

// ======================= fused ec_l + ab_{l+1} (or + fc_dec if last) =======================
// r16 ALL-RESIDENT structure (best: 253.7us). 512-thr blocks (8 waves), one 16-node
// group per block, grid = ngroups = 625 <= resident capacity -> every block runs
// concurrently. Each wave: 2 nodes (ec via 32x32x16 MFMA, W2 LDS fragment-major,
// single live f32x16 acc), then 2 ab j-tiles reusing one hlds A-frag read.
// Edges from the fixed-stride slot table (cnt/eltab) — no rowptr indirection.
// NOTE (r17 lesson, reaffirming r2/r3): do NOT add a min-waves launch bound or
// widen the live set (dual-node dA+dB) — the allocator spills to scratch
// (76 MB/dispatch WRITE_SIZE) rather than refusing; ec sits in a narrow ~100-128
// register corridor.
__global__ __launch_bounds__(512) void fused_conv(const _Float16* __restrict__ Acur,
                                                  const _Float16* __restrict__ Bcur,
                                                  const _Float16* __restrict__ W2T_l,
                                                  const float* __restrict__ b2_l,
                                                  const int* __restrict__ cnt,
                                                  const int* __restrict__ eltab,
                                                  const _Float16* __restrict__ WABT_n,
                                                  const float* __restrict__ biasAB_n,
                                                  _Float16* __restrict__ Anxt,
                                                  _Float16* __restrict__ Bnxt,
                                                  const _Float16* __restrict__ dWT,
                                                  const float* __restrict__ db,
                                                  float* __restrict__ out,
                                                  int last, int n) {
    __shared__ _Float16 w2s[2048 * 8];     // 32 KB, fragment-major (0-conflict, r3)
    __shared__ float b2s[HID];
    __shared__ _Float16 hlds[16][136];

    int tid = threadIdx.x;
    #pragma unroll
    for (int i = 0; i < 4; i++) {
        int fid = i * 512 + tid;           // 0..2047
        int ln = fid & 63;
        int grp = fid >> 6;                // kb*4+cb
        int kb = grp >> 2;
        int cb = grp & 3;
        *(half8*)(w2s + (size_t)fid * 8) =
            load_h8(W2T_l + (size_t)(cb * 32 + (ln & 31)) * HID + kb * 16 + (ln >> 5) * 8);
    }
    if (tid < HID) b2s[tid] = b2_l[tid];
    __syncthreads();

    int lane = tid & 63;
    int wv = tid >> 6;          // 0..7
    int er = lane & 31;
    int hi = lane >> 5;
    int c = lane & 15;
    int kq = lane >> 4;

    int g = blockIdx.x;
    int gbase = g * 16;

    // this wave's two nodes: rows wv and wv+8 of the group
    int vA = gbase + wv;
    int vB = gbase + wv + 8;
    int dgA = 0, dgB = 0;
    if (vA < n) { dgA = cnt[vA]; dgA = (dgA > ECAP) ? ECAP : dgA; }
    if (vB < n) { dgB = cnt[vB]; dgB = (dgB > ECAP) ? ECAP : dgB; }
    int srcA = (er < dgA) ? eltab[(size_t)vA * ECAP + er] : vA;
    int srcB = (er < dgB) ? eltab[(size_t)vB * ECAP + er] : vB;   // issued early

    // ---- ec for node (v, dg, src0) -> hlds[row] ----
    auto ec_node = [&](int v, int dg, int src0, int row) {
        float macc0 = -3.0e38f, macc1 = -3.0e38f, macc2 = -3.0e38f, macc3 = -3.0e38f;
        if (v < n) {
            int ntile = (dg + 32) >> 5;    // ceil((dg+1)/32), pad = self-loop
            int src = src0;
            for (int tI = 0; tI < ntile; tI++) {
                const _Float16* ap = Acur + (size_t)v * HID + hi * 8;
                const _Float16* bp = Bcur + (size_t)src * HID + hi * 8;
                half8 s[8];
                #pragma unroll
                for (int kb = 0; kb < 8; kb++) {
                    half8 t2 = load_h8(ap + kb * 16) + load_h8(bp + kb * 16);
                    #pragma unroll
                    for (int e2 = 0; e2 < 8; e2++) t2[e2] = (t2[e2] > (_Float16)0) ? t2[e2] : (_Float16)0;
                    s[kb] = t2;
                }
                int en = (tI + 1) * 32 + er;
                int srcn = (tI + 1 < ntile && en < dg) ? eltab[(size_t)v * ECAP + en] : v;

#define CB_BLOCK(CB, MREF)                                                              \
                {                                                                       \
                    f32x16 d;                                                           \
                    _Pragma("unroll")                                                   \
                    for (int e2 = 0; e2 < 16; e2++) d[e2] = 0.f;                        \
                    _Pragma("unroll")                                                   \
                    for (int kb = 0; kb < 8; kb++) {                                    \
                        half8 w = *(const half8*)(w2s + ((size_t)((kb * 4 + CB) * 64 + lane)) * 8); \
                        d = __builtin_amdgcn_mfma_f32_32x32x16_f16(s[kb], w, d, 0, 0, 0); \
                    }                                                                   \
                    float m0 = fmaxf(fmaxf(d[0], d[1]), fmaxf(d[2], d[3]));             \
                    float m1 = fmaxf(fmaxf(d[4], d[5]), fmaxf(d[6], d[7]));             \
                    float m2 = fmaxf(fmaxf(d[8], d[9]), fmaxf(d[10], d[11]));           \
                    float m3 = fmaxf(fmaxf(d[12], d[13]), fmaxf(d[14], d[15]));         \
                    MREF = fmaxf(MREF, fmaxf(fmaxf(m0, m1), fmaxf(m2, m3)));            \
                }
                CB_BLOCK(0, macc0)
                __builtin_amdgcn_sched_barrier(0);
                CB_BLOCK(1, macc1)
                __builtin_amdgcn_sched_barrier(0);
                CB_BLOCK(2, macc2)
                __builtin_amdgcn_sched_barrier(0);
                CB_BLOCK(3, macc3)
#undef CB_BLOCK
                src = srcn;
            }
        }
        float m0 = fmaxf(macc0, __shfl_xor(macc0, 32)) + b2s[er];
        float m1 = fmaxf(macc1, __shfl_xor(macc1, 32)) + b2s[32 + er];
        float m2 = fmaxf(macc2, __shfl_xor(macc2, 32)) + b2s[64 + er];
        float m3 = fmaxf(macc3, __shfl_xor(macc3, 32)) + b2s[96 + er];
        if (lane < 32) {
            hlds[row][er]      = (_Float16)m0;
            hlds[row][32 + er] = (_Float16)m1;
            hlds[row][64 + er] = (_Float16)m2;
            hlds[row][96 + er] = (_Float16)m3;
        }
    };

    ec_node(vA, dgA, srcA, wv);
    ec_node(vB, dgB, srcB, wv + 8);
    __syncthreads();

    if (!last) {
        // ---- ab phase: this wave does j-tiles wv and wv+8 (A-frags read once) ----
        half8 a[4];
        #pragma unroll
        for (int kb = 0; kb < 4; kb++)
            a[kb] = load_h8(&hlds[c][kb * 32 + kq * 8]);
        #pragma unroll
        for (int p = 0; p < 2; p++) {
            int jt = wv + p * 8;           // 0..15
            int wrow = jt * 16 + c;        // output col 0..255
            f32x4 acc = {0.f, 0.f, 0.f, 0.f};
            #pragma unroll
            for (int kb = 0; kb < 4; kb++) {
                half8 b = load_h8(WABT_n + (size_t)wrow * HID + kb * 32 + kq * 8);
                acc = __builtin_amdgcn_mfma_f32_16x16x32_f16(a[kb], b, acc, 0, 0, 0);
            }
            float bv = biasAB_n[wrow];
            _Float16* dst = (wrow < HID) ? Anxt : Bnxt;
            int dcol = wrow & (HID - 1);
            #pragma unroll
            for (int r = 0; r < 4; r++) {
                int row = gbase + kq * 4 + r;
                if (row < n) dst[(size_t)row * HID + dcol] = (_Float16)(acc[r] + bv);
            }
        }
    } else if (wv == 0) {
        // ---- fc_dec: out[gbase..+16][16] = h @ dWT^T + db ----
        half8 a[4];
        #pragma unroll
        for (int kb = 0; kb < 4; kb++)
            a[kb] = load_h8(&hlds[c][kb * 32 + kq * 8]);
        f32x4 acc = {0.f, 0.f, 0.f, 0.f};
        #pragma unroll
        for (int kb = 0; kb < 4; kb++) {
            half8 b = load_h8(dWT + (size_t)c * HID + kb * 32 + kq * 8);
            acc = __builtin_amdgcn_mfma_f32_16x16x32_f16(a[kb], b, acc, 0, 0, 0);
        }
        float bv = db[c];
        #pragma unroll
        for (int r = 0; r < 4; r++) {
            int row = gbase + kq * 4 + r;
            if (row < n) out[(size_t)row * NDIM + c] = acc[r] + bv;
        }
    }
}

// ---------------- host ----------------
extern "C" void kernel_launch(void* const* d_in, const int* in_sizes, int n_in,
                              void* d_out, int out_size, void* d_ws, size_t ws_size,
                              hipStream_t stream) {
    const float* x   = (const float*)d_in[0];
    const int*   ei  = (const int*)d_in[1];
    const float* t   = (const float*)d_in[2];
    const float* neW = (const float*)d_in[3];
    const float* neb = (const float*)d_in[4];
    const float* cW1 = (const float*)d_in[5];
    const float* cb1 = (const float*)d_in[6];
    const float* cW2 = (const float*)d_in[7];
    const float* cb2 = (const float*)d_in[8];
    const float* eW  = (const float*)d_in[9];
    const float* eb  = (const float*)d_in[10];
    const float* dW  = (const float*)d_in[11];
    const float* db  = (const float*)d_in[12];
    const float* tpW = (const float*)d_in[13];
    const float* tpb = (const float*)d_in[14];

    int N = in_sizes[0] / NDIM;
    int E = in_sizes[1] / 2;

    char* w = (char*)d_ws;
    auto alloc = [&](size_t bytes) {
        void* p = (void*)w;
        w += (bytes + 255) & ~(size_t)255;
        return p;
    };
    _Float16*  Atab0  = (_Float16*)alloc((size_t)N * HID * 2);
    _Float16*  Btab0  = (_Float16*)alloc((size_t)N * HID * 2);
    _Float16*  Atab1  = (_Float16*)alloc((size_t)N * HID * 2);
    _Float16*  Btab1  = (_Float16*)alloc((size_t)N * HID * 2);
    _Float16*  WABT   = (_Float16*)alloc((size_t)NCONV * 2 * HID * HID * 2);
    _Float16*  W2T    = (_Float16*)alloc((size_t)NCONV * HID * HID * 2);
    _Float16*  dWT    = (_Float16*)alloc((size_t)16 * HID * 2);
    _Float16*  eW16   = (_Float16*)alloc((size_t)HID * HID * 2);
    _Float16*  WENC   = (_Float16*)alloc((size_t)2 * HID * HID * 2);
    float*     biasAB = (float*)alloc((size_t)NCONV * 256 * 4);
    float*     biasENC= (float*)alloc((size_t)256 * 4);
    int*       cnt    = (int*)alloc((size_t)N * 4);
    int*       eltab  = (int*)alloc((size_t)N * ECAP * 4);

    // 1: zero slot cursors
    hipMemsetAsync(cnt, 0, (size_t)N * 4, stream);
    // 2: weights + slot-table edge fill
    int prep_total = NCONV * HID * HID + 16 * HID + NCONV * 256 + HID * HID;
    prep_weights<<<(prep_total + 255) / 256, 256, 0, stream>>>(cW1, cW2, dW, cb1, eW, ei,
                                                               WABT, W2T, dWT, biasAB,
                                                               eW16, cnt, eltab, E);
    // 3: node emb + layer-0 ab + enc fold
    int nmt = (N + 15) / 16;
    node_emb_ab<<<nmt + 17, 512, 0, stream>>>(x, t, tpW, tpb, neW, neb,
                                              WABT, biasAB, Atab0, Btab0,
                                              eW16, WABT + (size_t)4 * 2 * HID * HID,
                                              cb1 + (size_t)4 * HID, eb, WENC, biasENC, N);

    // 4..11: fused conv layers
    for (int l = 0; l < NCONV; l++) {
        const _Float16* Acur = (l & 1) ? Atab1 : Atab0;
        const _Float16* Bcur = (l & 1) ? Btab1 : Btab0;
        _Float16* Anxt = (l & 1) ? Atab0 : Atab1;
        _Float16* Bnxt = (l & 1) ? Btab0 : Btab1;
        int ln = (l + 1 < NCONV) ? (l + 1) : 0;   // dummy (unused) when last
        const _Float16* wabn = (l == 3) ? WENC : WABT + (size_t)ln * 2 * HID * HID;
        const float*    babn = (l == 3) ? biasENC : biasAB + (size_t)ln * 256;
        fused_conv<<<nmt, 512, 0, stream>>>(Acur, Bcur,
                                            W2T + (size_t)l * HID * HID,
                                            cb2 + (size_t)l * HID,
                                            cnt, eltab,
                                            wabn, babn,
                                            Anxt, Bnxt,
                                            dWT, db, (float*)d_out,
                                            (l == NCONV - 1) ? 1 : 0, N);
    }
}

// Round 19
// 243.363 us; speedup vs baseline: 1.6958x; 1.0435x over previous
//
#include <hip/hip_runtime.h>
#include <hip/hip_fp16.h>

typedef _Float16 half8 __attribute__((ext_vector_type(8)));
typedef float f32x4 __attribute__((ext_vector_type(4)));
typedef float f32x16 __attribute__((ext_vector_type(16)));

#define HID 128
#define NDIM 16
#define NCONV 8
#define ECAP 64   // slot capacity per node; Poisson(16) max deg ~40 << 64

static __device__ __forceinline__ half8 load_h8(const _Float16* p) {
    return *(const half8*)p;
}

// ---------------- weight prep (+ cnt zeroing tail) ----------------
// WABT[l] rows j<128: W1A_T[j][k]=W1[k][j]-W1[128+k][j]; rows 128+j: W1B_T[j][k]=W1[128+k][j]
// W2T[l][j][k] = W2[k][j].  Tails: dWT, biasAB, eW16 (f16 cast), cnt[]=0.
// Edge fill moved to node_emb_ab (dispatch boundary orders zero->fill->consume).
__global__ void prep_weights(const float* __restrict__ W1, const float* __restrict__ W2,
                             const float* __restrict__ dW, const float* __restrict__ b1,
                             const float* __restrict__ eW,
                             _Float16* __restrict__ WABT, _Float16* __restrict__ W2T,
                             _Float16* __restrict__ dWT, float* __restrict__ biasAB,
                             _Float16* __restrict__ eW16,
                             int* __restrict__ cnt, int n) {
    int idx = blockIdx.x * blockDim.x + threadIdx.x;
    int total = NCONV * HID * HID;
    if (idx < total) {
        int l = idx / (HID * HID);
        int r = idx % (HID * HID);
        int k = r / HID;        // slow: input row
        int j = r % HID;        // fast: input col -> coalesced loads
        const float* w1 = W1 + (size_t)l * 2 * HID * HID;
        float top = w1[k * HID + j];
        float bot = w1[(HID + k) * HID + j];
        _Float16* wab = WABT + (size_t)l * 2 * HID * HID;
        wab[j * HID + k] = (_Float16)(top - bot);
        wab[(HID + j) * HID + k] = (_Float16)bot;
        const float* w2 = W2 + (size_t)l * HID * HID;
        W2T[(size_t)l * HID * HID + j * HID + k] = (_Float16)w2[k * HID + j];
    } else if (idx < total + 16 * HID) {
        int r = idx - total;
        int j = r / HID;        // 0..15
        int k = r % HID;
        dWT[j * HID + k] = (_Float16)dW[k * NDIM + j];
    } else if (idx < total + 16 * HID + NCONV * 256) {
        int r = idx - total - 16 * HID;
        int l = r >> 8;
        int c = r & 255;
        biasAB[l * 256 + c] = (c < HID) ? b1[l * HID + c] : 0.f;
    } else if (idx < total + 16 * HID + NCONV * 256 + HID * HID) {
        int r = idx - total - 16 * HID - NCONV * 256;
        eW16[r] = (_Float16)eW[r];           // straight cast, coalesced
    } else if (idx < total + 16 * HID + NCONV * 256 + HID * HID + n) {
        cnt[idx - total - 16 * HID - NCONV * 256 - HID * HID] = 0;
    }
}

// ---------------- edge fill + node_emb + layer-0 ab + enc-fold (one dispatch) ----------------
// ALL blocks first grid-stride the slot-table edge fill (eltab[dst][slot]=src via
// atomic cursor; slot order race-dependent but ec's max is order-invariant ->
// deterministic OUTPUT). Then: group blocks do node-emb + ab0; extra blocks enc-fold.
__global__ __launch_bounds__(512) void node_emb_ab(const float* __restrict__ x,
                                                   const float* __restrict__ t,
                                                   const float* __restrict__ tpW,
                                                   const float* __restrict__ tpb,
                                                   const float* __restrict__ neW,
                                                   const float* __restrict__ neb,
                                                   const _Float16* __restrict__ WABT0,
                                                   const float* __restrict__ biasAB0,
                                                   _Float16* __restrict__ Atab,
                                                   _Float16* __restrict__ Btab,
                                                   const _Float16* __restrict__ eW16,
                                                   const _Float16* __restrict__ WABT4old,
                                                   const float* __restrict__ b1_4,
                                                   const float* __restrict__ eb,
                                                   _Float16* __restrict__ WENC,
                                                   float* __restrict__ biasENC,
                                                   const int* __restrict__ ei,
                                                   int* __restrict__ cnt,
                                                   int* __restrict__ eltab,
                                                   int n, int E) {
    int bid = blockIdx.x;
    int tid = threadIdx.x;

    // ---- slot-table edge fill (all blocks; consumers are in later dispatches) ----
    {
        int gtid = bid * 512 + tid;
        int gsz = gridDim.x * 512;
        for (int e = gtid; e < E; e += gsz) {
            int dv = ei[E + e];
            int pos = atomicAdd(&cnt[dv], 1);
            if (pos < ECAP) eltab[(size_t)dv * ECAP + pos] = ei[e];
        }
    }

    int ngroups = (n + 15) >> 4;
    int lane = tid & 63;
    int wv = tid >> 6;
    int c = lane & 15;
    int kq = lane >> 4;

    if (bid >= ngroups) {
        int xb = bid - ngroups;
        if (xb < 16) {           // enc-fold GEMM: 8 output tiles per block
            int gw = xb * 8 + wv;          // 0..127
            int jt = gw >> 3;              // 0..15 (256 output cols)
            int kt = gw & 7;               // 0..7  (128 k)
            half8 a[4], b[4];
            #pragma unroll
            for (int kb = 0; kb < 4; kb++) {
                a[kb] = load_h8(eW16 + (size_t)(kt * 16 + c) * HID + kb * 32 + kq * 8);
                b[kb] = load_h8(WABT4old + (size_t)(jt * 16 + c) * HID + kb * 32 + kq * 8);
            }
            f32x4 acc = {0.f, 0.f, 0.f, 0.f};
            #pragma unroll
            for (int kb = 0; kb < 4; kb++)
                acc = __builtin_amdgcn_mfma_f32_16x16x32_f16(a[kb], b[kb], acc, 0, 0, 0);
            #pragma unroll
            for (int r = 0; r < 4; r++)
                WENC[(size_t)(jt * 16 + c) * HID + kt * 16 + kq * 4 + r] = (_Float16)acc[r];
        } else if (tid < 256) {  // enc-fold biases
            float acc = (tid < HID) ? b1_4[tid] : 0.f;
            const _Float16* row = WABT4old + (size_t)tid * HID;
            for (int q = 0; q < HID; q++) acc += eb[q] * (float)row[q];
            biasENC[tid] = acc;
        }
        return;
    }

    __shared__ float sc[64];
    __shared__ float temb[NDIM];
    __shared__ _Float16 hlds[16][136];
    float tv = t[0];
    if (tid < 32) {
        float f = expf(-4.0f + 8.0f * (float)tid / 31.0f);
        sc[tid] = sinf(tv * f);
        sc[32 + tid] = cosf(tv * f);
    }
    __syncthreads();
    if (tid < 16) {
        float acc = tpb[tid];
        for (int k = 0; k < 64; k++) acc += sc[k] * tpW[k * NDIM + tid];
        temb[tid] = acc;
    }
    __syncthreads();

    int gbase = bid * 16;
    for (int idx = tid; idx < 16 * HID; idx += 512) {
        int r = idx >> 7;
        int j = idx & 127;
        int v = gbase + r;
        float acc = 0.f;
        if (v < n) {
            const float* xr = x + (size_t)v * NDIM;
            acc = neb[j];
            #pragma unroll
            for (int d = 0; d < NDIM; d++) acc += (xr[d] + temb[d]) * neW[d * HID + j];
        }
        hlds[r][j] = (_Float16)acc;
    }
    __syncthreads();

    // ab phase (identical to fused_conv's)
    half8 a[4];
    #pragma unroll
    for (int kb = 0; kb < 4; kb++)
        a[kb] = load_h8(&hlds[c][kb * 32 + kq * 8]);
    #pragma unroll
    for (int p = 0; p < 2; p++) {
        int jt = wv + p * 8;
        int wrow = jt * 16 + c;
        f32x4 acc = {0.f, 0.f, 0.f, 0.f};
        #pragma unroll
        for (int kb = 0; kb < 4; kb++) {
            half8 b = load_h8(WABT0 + (size_t)wrow * HID + kb * 32 + kq * 8);
            acc = __builtin_amdgcn_mfma_f32_16x16x32_f16(a[kb], b, acc, 0, 0, 0);
        }
        float bv = biasAB0[wrow];
        _Float16* dst = (wrow < HID) ? Atab : Btab;
        int dcol = wrow & (HID - 1);
        #pragma unroll
        for (int r = 0; r < 4; r++) {
            int row = gbase + kq * 4 + r;
            if (row < n) dst[(size_t)row * HID + dcol] = (_Float16)(acc[r] + bv);
        }
    }
}

// ======================= fused ec_l + ab_{l+1} (or + fc_dec if last) =======================
// r16 ALL-RESIDENT structure + DEGREE-PACKED dual-node tiles: when BOTH of a wave's
// nodes have deg<=15 (P~0.22/pair), their edges pack into ONE 32x32 tile (rows 0-15 =
// node A's edges+self-pad, rows 16-31 = node B's). C layout row=(reg&3)+8*(reg>>2)+4*hi
// (HW-verified) puts regs 0-7 on rows 0-15 and regs 8-15 on rows 16-31, so the max
// splits per-node. Halves MFMA+LDS+relu AND the wave's serial latency chain for those
// pairs. Same live set; wave-uniform branch; serial fallback otherwise.
// NOTE (r17 lesson, reaffirming r2/r3): NO min-waves launch bound, NO dual live
// accumulators — the allocator spills to scratch rather than refusing; ec sits in a
// narrow ~100-128 register corridor.
__global__ __launch_bounds__(512) void fused_conv(const _Float16* __restrict__ Acur,
                                                  const _Float16* __restrict__ Bcur,
                                                  const _Float16* __restrict__ W2T_l,
                                                  const float* __restrict__ b2_l,
                                                  const int* __restrict__ cnt,
                                                  const int* __restrict__ eltab,
                                                  const _Float16* __restrict__ WABT_n,
                                                  const float* __restrict__ biasAB_n,
                                                  _Float16* __restrict__ Anxt,
                                                  _Float16* __restrict__ Bnxt,
                                                  const _Float16* __restrict__ dWT,
                                                  const float* __restrict__ db,
                                                  float* __restrict__ out,
                                                  int last, int n) {
    __shared__ _Float16 w2s[2048 * 8];     // 32 KB, fragment-major (0-conflict, r3)
    __shared__ float b2s[HID];
    __shared__ _Float16 hlds[16][136];

    int tid = threadIdx.x;
    #pragma unroll
    for (int i = 0; i < 4; i++) {
        int fid = i * 512 + tid;           // 0..2047
        int ln = fid & 63;
        int grp = fid >> 6;                // kb*4+cb
        int kb = grp >> 2;
        int cb = grp & 3;
        *(half8*)(w2s + (size_t)fid * 8) =
            load_h8(W2T_l + (size_t)(cb * 32 + (ln & 31)) * HID + kb * 16 + (ln >> 5) * 8);
    }
    if (tid < HID) b2s[tid] = b2_l[tid];
    __syncthreads();

    int lane = tid & 63;
    int wv = tid >> 6;          // 0..7
    int er = lane & 31;
    int hi = lane >> 5;
    int c = lane & 15;
    int kq = lane >> 4;

    int g = blockIdx.x;
    int gbase = g * 16;

    // this wave's two nodes: rows wv and wv+8 of the group
    int vA = gbase + wv;
    int vB = gbase + wv + 8;
    int dgA = 0, dgB = 0;
    if (vA < n) { dgA = cnt[vA]; dgA = (dgA > ECAP) ? ECAP : dgA; }
    if (vB < n) { dgB = cnt[vB]; dgB = (dgB > ECAP) ? ECAP : dgB; }

    // ---- write helper: merge row-complement lanes, add bias, store to hlds ----
    auto write_row = [&](int row, float m0, float m1, float m2, float m3) {
        float a0 = fmaxf(m0, __shfl_xor(m0, 32)) + b2s[er];
        float a1 = fmaxf(m1, __shfl_xor(m1, 32)) + b2s[32 + er];
        float a2 = fmaxf(m2, __shfl_xor(m2, 32)) + b2s[64 + er];
        float a3 = fmaxf(m3, __shfl_xor(m3, 32)) + b2s[96 + er];
        if (lane < 32) {
            hlds[row][er]      = (_Float16)a0;
            hlds[row][32 + er] = (_Float16)a1;
            hlds[row][64 + er] = (_Float16)a2;
            hlds[row][96 + er] = (_Float16)a3;
        }
    };

    bool packed = (vB < n) && (dgA <= 15) && (dgB <= 15);
    if (packed) {
        // ---- ONE 32-row tile covering both nodes ----
        int pnode = (er < 16) ? vA : vB;
        int pe = er & 15;
        int pdg = (er < 16) ? dgA : dgB;
        int psrc = (pe < pdg) ? eltab[(size_t)pnode * ECAP + pe] : pnode;   // self-pad
        const _Float16* ap = Acur + (size_t)pnode * HID + hi * 8;
        const _Float16* bp = Bcur + (size_t)psrc * HID + hi * 8;
        half8 s[8];
        #pragma unroll
        for (int kb = 0; kb < 8; kb++) {
            half8 t2 = load_h8(ap + kb * 16) + load_h8(bp + kb * 16);
            #pragma unroll
            for (int e2 = 0; e2 < 8; e2++) t2[e2] = (t2[e2] > (_Float16)0) ? t2[e2] : (_Float16)0;
            s[kb] = t2;
        }
        float mA0, mA1, mA2, mA3, mB0, mB1, mB2, mB3;
#define CBP(CB, MA, MB)                                                                 \
        {                                                                               \
            f32x16 d;                                                                   \
            _Pragma("unroll")                                                           \
            for (int e2 = 0; e2 < 16; e2++) d[e2] = 0.f;                                \
            _Pragma("unroll")                                                           \
            for (int kb = 0; kb < 8; kb++) {                                            \
                half8 w = *(const half8*)(w2s + ((size_t)((kb * 4 + CB) * 64 + lane)) * 8); \
                d = __builtin_amdgcn_mfma_f32_32x32x16_f16(s[kb], w, d, 0, 0, 0);       \
            }                                                                           \
            float tA = fmaxf(fmaxf(fmaxf(d[0], d[1]), fmaxf(d[2], d[3])),               \
                             fmaxf(fmaxf(d[4], d[5]), fmaxf(d[6], d[7])));              \
            float tB = fmaxf(fmaxf(fmaxf(d[8], d[9]), fmaxf(d[10], d[11])),             \
                             fmaxf(fmaxf(d[12], d[13]), fmaxf(d[14], d[15])));          \
            MA = tA; MB = tB;                                                           \
        }
        CBP(0, mA0, mB0)
        __builtin_amdgcn_sched_barrier(0);
        CBP(1, mA1, mB1)
        __builtin_amdgcn_sched_barrier(0);
        CBP(2, mA2, mB2)
        __builtin_amdgcn_sched_barrier(0);
        CBP(3, mA3, mB3)
#undef CBP
        write_row(wv, mA0, mA1, mA2, mA3);
        write_row(wv + 8, mB0, mB1, mB2, mB3);
    } else {
        // ---- serial fallback: the r16 per-node path ----
        int srcA = (er < dgA) ? eltab[(size_t)vA * ECAP + er] : vA;
        int srcB = (er < dgB) ? eltab[(size_t)vB * ECAP + er] : vB;

        auto ec_node = [&](int v, int dg, int src0, int row) {
            float macc0 = -3.0e38f, macc1 = -3.0e38f, macc2 = -3.0e38f, macc3 = -3.0e38f;
            if (v < n) {
                int ntile = (dg + 32) >> 5;    // ceil((dg+1)/32), pad = self-loop
                int src = src0;
                for (int tI = 0; tI < ntile; tI++) {
                    const _Float16* ap = Acur + (size_t)v * HID + hi * 8;
                    const _Float16* bp = Bcur + (size_t)src * HID + hi * 8;
                    half8 s[8];
                    #pragma unroll
                    for (int kb = 0; kb < 8; kb++) {
                        half8 t2 = load_h8(ap + kb * 16) + load_h8(bp + kb * 16);
                        #pragma unroll
                        for (int e2 = 0; e2 < 8; e2++) t2[e2] = (t2[e2] > (_Float16)0) ? t2[e2] : (_Float16)0;
                        s[kb] = t2;
                    }
                    int en = (tI + 1) * 32 + er;
                    int srcn = (tI + 1 < ntile && en < dg) ? eltab[(size_t)v * ECAP + en] : v;

#define CB_BLOCK(CB, MREF)                                                              \
                    {                                                                   \
                        f32x16 d;                                                       \
                        _Pragma("unroll")                                               \
                        for (int e2 = 0; e2 < 16; e2++) d[e2] = 0.f;                    \
                        _Pragma("unroll")                                               \
                        for (int kb = 0; kb < 8; kb++) {                                \
                            half8 w = *(const half8*)(w2s + ((size_t)((kb * 4 + CB) * 64 + lane)) * 8); \
                            d = __builtin_amdgcn_mfma_f32_32x32x16_f16(s[kb], w, d, 0, 0, 0); \
                        }                                                               \
                        float m0 = fmaxf(fmaxf(d[0], d[1]), fmaxf(d[2], d[3]));         \
                        float m1 = fmaxf(fmaxf(d[4], d[5]), fmaxf(d[6], d[7]));         \
                        float m2 = fmaxf(fmaxf(d[8], d[9]), fmaxf(d[10], d[11]));       \
                        float m3 = fmaxf(fmaxf(d[12], d[13]), fmaxf(d[14], d[15]));     \
                        MREF = fmaxf(MREF, fmaxf(fmaxf(m0, m1), fmaxf(m2, m3)));        \
                    }
                    CB_BLOCK(0, macc0)
                    __builtin_amdgcn_sched_barrier(0);
                    CB_BLOCK(1, macc1)
                    __builtin_amdgcn_sched_barrier(0);
                    CB_BLOCK(2, macc2)
                    __builtin_amdgcn_sched_barrier(0);
                    CB_BLOCK(3, macc3)
#undef CB_BLOCK
                    src = srcn;
                }
            }
            write_row(row, macc0, macc1, macc2, macc3);
        };

        ec_node(vA, dgA, srcA, wv);
        ec_node(vB, dgB, srcB, wv + 8);
    }
    __syncthreads();

    if (!last) {
        // ---- ab phase: this wave does j-tiles wv and wv+8 (A-frags read once) ----
        half8 a[4];
        #pragma unroll
        for (int kb = 0; kb < 4; kb++)
            a[kb] = load_h8(&hlds[c][kb * 32 + kq * 8]);
        #pragma unroll
        for (int p = 0; p < 2; p++) {
            int jt = wv + p * 8;           // 0..15
            int wrow = jt * 16 + c;        // output col 0..255
            f32x4 acc = {0.f, 0.f, 0.f, 0.f};
            #pragma unroll
            for (int kb = 0; kb < 4; kb++) {
                half8 b = load_h8(WABT_n + (size_t)wrow * HID + kb * 32 + kq * 8);
                acc = __builtin_amdgcn_mfma_f32_16x16x32_f16(a[kb], b, acc, 0, 0, 0);
            }
            float bv = biasAB_n[wrow];
            _Float16* dst = (wrow < HID) ? Anxt : Bnxt;
            int dcol = wrow & (HID - 1);
            #pragma unroll
            for (int r = 0; r < 4; r++) {
                int row = gbase + kq * 4 + r;
                if (row < n) dst[(size_t)row * HID + dcol] = (_Float16)(acc[r] + bv);
            }
        }
    } else if (wv == 0) {
        // ---- fc_dec: out[gbase..+16][16] = h @ dWT^T + db ----
        half8 a[4];
        #pragma unroll
        for (int kb = 0; kb < 4; kb++)
            a[kb] = load_h8(&hlds[c][kb * 32 + kq * 8]);
        f32x4 acc = {0.f, 0.f, 0.f, 0.f};
        #pragma unroll
        for (int kb = 0; kb < 4; kb++) {
            half8 b = load_h8(dWT + (size_t)c * HID + kb * 32 + kq * 8);
            acc = __builtin_amdgcn_mfma_f32_16x16x32_f16(a[kb], b, acc, 0, 0, 0);
        }
        float bv = db[c];
        #pragma unroll
        for (int r = 0; r < 4; r++) {
            int row = gbase + kq * 4 + r;
            if (row < n) out[(size_t)row * NDIM + c] = acc[r] + bv;
        }
    }
}

// ---------------- host ----------------
extern "C" void kernel_launch(void* const* d_in, const int* in_sizes, int n_in,
                              void* d_out, int out_size, void* d_ws, size_t ws_size,
                              hipStream_t stream) {
    const float* x   = (const float*)d_in[0];
    const int*   ei  = (const int*)d_in[1];
    const float* t   = (const float*)d_in[2];
    const float* neW = (const float*)d_in[3];
    const float* neb = (const float*)d_in[4];
    const float* cW1 = (const float*)d_in[5];
    const float* cb1 = (const float*)d_in[6];
    const float* cW2 = (const float*)d_in[7];
    const float* cb2 = (const float*)d_in[8];
    const float* eW  = (const float*)d_in[9];
    const float* eb  = (const float*)d_in[10];
    const float* dW  = (const float*)d_in[11];
    const float* db  = (const float*)d_in[12];
    const float* tpW = (const float*)d_in[13];
    const float* tpb = (const float*)d_in[14];

    int N = in_sizes[0] / NDIM;
    int E = in_sizes[1] / 2;

    char* w = (char*)d_ws;
    auto alloc = [&](size_t bytes) {
        void* p = (void*)w;
        w += (bytes + 255) & ~(size_t)255;
        return p;
    };
    _Float16*  Atab0  = (_Float16*)alloc((size_t)N * HID * 2);
    _Float16*  Btab0  = (_Float16*)alloc((size_t)N * HID * 2);
    _Float16*  Atab1  = (_Float16*)alloc((size_t)N * HID * 2);
    _Float16*  Btab1  = (_Float16*)alloc((size_t)N * HID * 2);
    _Float16*  WABT   = (_Float16*)alloc((size_t)NCONV * 2 * HID * HID * 2);
    _Float16*  W2T    = (_Float16*)alloc((size_t)NCONV * HID * HID * 2);
    _Float16*  dWT    = (_Float16*)alloc((size_t)16 * HID * 2);
    _Float16*  eW16   = (_Float16*)alloc((size_t)HID * HID * 2);
    _Float16*  WENC   = (_Float16*)alloc((size_t)2 * HID * HID * 2);
    float*     biasAB = (float*)alloc((size_t)NCONV * 256 * 4);
    float*     biasENC= (float*)alloc((size_t)256 * 4);
    int*       cnt    = (int*)alloc((size_t)N * 4);
    int*       eltab  = (int*)alloc((size_t)N * ECAP * 4);

    // 1: weights + cnt zeroing (edge fill happens in node_emb_ab, next dispatch)
    int prep_total = NCONV * HID * HID + 16 * HID + NCONV * 256 + HID * HID + N;
    prep_weights<<<(prep_total + 255) / 256, 256, 0, stream>>>(cW1, cW2, dW, cb1, eW,
                                                               WABT, W2T, dWT, biasAB,
                                                               eW16, cnt, N);
    // 2: edge fill + node emb + layer-0 ab + enc fold
    int nmt = (N + 15) / 16;
    node_emb_ab<<<nmt + 17, 512, 0, stream>>>(x, t, tpW, tpb, neW, neb,
                                              WABT, biasAB, Atab0, Btab0,
                                              eW16, WABT + (size_t)4 * 2 * HID * HID,
                                              cb1 + (size_t)4 * HID, eb, WENC, biasENC,
                                              ei, cnt, eltab, N, E);

    // 3..10: fused conv layers
    for (int l = 0; l < NCONV; l++) {
        const _Float16* Acur = (l & 1) ? Atab1 : Atab0;
        const _Float16* Bcur = (l & 1) ? Btab1 : Btab0;
        _Float16* Anxt = (l & 1) ? Atab0 : Atab1;
        _Float16* Bnxt = (l & 1) ? Btab0 : Btab1;
        int ln = (l + 1 < NCONV) ? (l + 1) : 0;   // dummy (unused) when last
        const _Float16* wabn = (l == 3) ? WENC : WABT + (size_t)ln * 2 * HID * HID;
        const float*    babn = (l == 3) ? biasENC : biasAB + (size_t)ln * 256;
        fused_conv<<<nmt, 512, 0, stream>>>(Acur, Bcur,
                                            W2T + (size_t)l * HID * HID,
                                            cb2 + (size_t)l * HID,
                                            cnt, eltab,
                                            wabn, babn,
                                            Anxt, Bnxt,
                                            dWT, db, (float*)d_out,
                                            (l == NCONV - 1) ? 1 : 0, N);
    }
}